// Round 1
// baseline (15132.463 us; speedup 1.0000x reference)
//
#include <hip/hip_runtime.h>
#include <math.h>

namespace {
constexpr int D = 1024;
constexpr int B = 16;
constexpr int T = 2048;
constexpr int L = 16;             // chunk length
constexpr int C = T / L;          // 128 chunks
constexpr float SR  = 0.999f;
constexpr float EPS = 1e-8f;

// workspace layout (float offsets); total ~12.6 MB
constexpr size_t WS_VA    = 0;
constexpr size_t WS_VB    = 1024;
constexpr size_t WS_SCALE = 2048;
constexpr size_t WS_WNT   = 4096;                      // Wn^T, 4 MB
constexpr size_t WS_PA    = WS_WNT + (size_t)D * D;    // power ping
constexpr size_t WS_PB    = WS_PA + (size_t)D * D;     // power pong
}

// ---------------- spectral norm helpers ----------------

// vout = W^T vin  (coalesced over output column j)
__global__ void mvT_kernel(const float* __restrict__ W, const float* __restrict__ vin,
                           float* __restrict__ vout) {
  int j = blockIdx.x * 256 + threadIdx.x;
  float acc = 0.f;
#pragma unroll 4
  for (int i = 0; i < D; ++i) acc += vin[i] * W[i * D + j];
  vout[j] = acc;
}

// vout = W vin  (one block per row, coalesced row dot)
__global__ void mvN_kernel(const float* __restrict__ W, const float* __restrict__ vin,
                           float* __restrict__ vout) {
  __shared__ float red[256];
  int i = blockIdx.x, tid = threadIdx.x;
  float acc = 0.f;
  for (int j = tid; j < D; j += 256) acc += W[i * D + j] * vin[j];
  red[tid] = acc; __syncthreads();
  for (int s = 128; s > 0; s >>= 1) {
    if (tid < s) red[tid] += red[tid + s];
    __syncthreads();
  }
  if (tid == 0) vout[i] = red[0];
}

// scale = SR / (||t6||/(||t5||+eps) + eps)
__global__ void scale_kernel(const float* __restrict__ t5, const float* __restrict__ t6,
                             float* __restrict__ scale_out) {
  __shared__ float r5[256], r6[256];
  int tid = threadIdx.x;
  float a5 = 0.f, a6 = 0.f;
  for (int i = tid; i < D; i += 256) { float x5 = t5[i], x6 = t6[i]; a5 += x5 * x5; a6 += x6 * x6; }
  r5[tid] = a5; r6[tid] = a6; __syncthreads();
  for (int s = 128; s > 0; s >>= 1) {
    if (tid < s) { r5[tid] += r5[tid + s]; r6[tid] += r6[tid + s]; }
    __syncthreads();
  }
  if (tid == 0) {
    float n5 = sqrtf(r5[0]), n6 = sqrtf(r6[0]);
    float sigma = n6 / (n5 + EPS);
    scale_out[0] = SR / (sigma + EPS);
  }
}

// WnT[d][e] = scale * W[e][d]
__global__ void transpose_scale_kernel(const float* __restrict__ W, const float* __restrict__ sc,
                                       float* __restrict__ WnT) {
  __shared__ float tile[32][33];
  float s = sc[0];
  int tx = threadIdx.x, ty = threadIdx.y;
  int bx = blockIdx.x, by = blockIdx.y;
#pragma unroll
  for (int k = 0; k < 4; ++k)
    tile[ty + 8 * k][tx] = W[(by * 32 + ty + 8 * k) * D + bx * 32 + tx];
  __syncthreads();
#pragma unroll
  for (int k = 0; k < 4; ++k)
    WnT[(bx * 32 + ty + 8 * k) * D + by * 32 + tx] = s * tile[tx][ty + 8 * k];
}

// O = S * S  (1024^3 f32 GEMM; used for (A^k)^T squarings since (A^2)^T = (A^T)^2)
__global__ void sq_kernel(const float* __restrict__ S, float* __restrict__ O) {
  __shared__ float As[16][68];
  __shared__ float Bs[16][68];
  int tid = threadIdx.x;
  int tx = tid & 15, ty = tid >> 4;
  int n0 = blockIdx.x * 64, m0 = blockIdx.y * 64;
  float acc[4][4] = {};
  for (int k0 = 0; k0 < D; k0 += 16) {
#pragma unroll
    for (int i = 0; i < 4; ++i) {
      int flat = tid + 256 * i;
      As[flat & 15][flat >> 4] = S[(m0 + (flat >> 4)) * D + k0 + (flat & 15)];
      Bs[flat >> 6][flat & 63] = S[(k0 + (flat >> 6)) * D + n0 + (flat & 63)];
    }
    __syncthreads();
#pragma unroll
    for (int k = 0; k < 16; ++k) {
      float a[4], b[4];
#pragma unroll
      for (int i = 0; i < 4; ++i) a[i] = As[k][ty * 4 + i];
#pragma unroll
      for (int j = 0; j < 4; ++j) b[j] = Bs[k][tx * 4 + j];
#pragma unroll
      for (int i = 0; i < 4; ++i)
#pragma unroll
        for (int j = 0; j < 4; ++j)
          acc[i][j] += a[i] * b[j];
    }
    __syncthreads();
  }
#pragma unroll
  for (int i = 0; i < 4; ++i)
#pragma unroll
    for (int j = 0; j < 4; ++j)
      O[(m0 + ty * 4 + i) * D + n0 + tx * 4 + j] = acc[i][j];
}

// h row 0 = h0; also stash s_0 = h0 at output slice 0
__global__ void init_h0_kernel(const float* __restrict__ h0, float* __restrict__ hbuf,
                               float* __restrict__ out) {
  int i = blockIdx.x * 256 + threadIdx.x;   // 4096 threads x float4 = 16384 floats
  float4 v = ((const float4*)h0)[i];
  ((float4*)hbuf)[i] = v;
  ((float4*)out)[i]  = v;
}

// ---------------- scan phases ----------------

__device__ __forceinline__ void dot4(float4& acc, float4 g, float4 a0, float4 a1,
                                     float4 a2, float4 a3) {
  acc.x += g.x * a0.x + g.y * a1.x + g.z * a2.x + g.w * a3.x;
  acc.y += g.x * a0.y + g.y * a1.y + g.z * a2.y + g.w * a3.y;
  acc.z += g.x * a0.z + g.y * a1.z + g.z * a2.z + g.w * a3.z;
  acc.w += g.x * a0.w + g.y * a1.w + g.z * a2.w + g.w * a3.w;
}

// Phase 1: per-chunk local recurrence, zero init:
//   hl_t = Wn*(x_t + hl_{t-1}) + bias,  stored into hbuf rows 1..T
// grid 256 = (chunk, b-half); block 256; each thread: 8 b x 4 e accumulators.
__global__ __launch_bounds__(256)
void phase1_kernel(const float* __restrict__ x, const float* __restrict__ WnT,
                   const float* __restrict__ bias, float* __restrict__ hbuf) {
  __shared__ float G[8 * 1024];     // g[b_local][d] = x + hl_prev, 32 KB
  const int tid = threadIdx.x;
  const int c  = blockIdx.x >> 1;
  const int bh = (blockIdx.x & 1) * 8;
  const float4* A4 = (const float4*)WnT;
  const float4* X4 = (const float4*)x;
  float4* H4 = (float4*)hbuf;
  float4* G4 = (float4*)G;
  const float4 bias4 = ((const float4*)bias)[tid];

  {
    const int r = c * L;            // first x row of the chunk
#pragma unroll
    for (int bl = 0; bl < 8; ++bl)
      G4[bl * 256 + tid] = X4[(r * 16 + bh + bl) * 256 + tid];
  }
  __syncthreads();

  for (int j = 1; j <= L; ++j) {
    float4 acc[8];
#pragma unroll
    for (int bl = 0; bl < 8; ++bl) acc[bl] = bias4;

#pragma unroll 4
    for (int d4 = 0; d4 < 256; ++d4) {
      const int abase = d4 * 1024 + tid;   // WnT row 4*d4, float4 col tid
      float4 a0 = A4[abase], a1 = A4[abase + 256], a2 = A4[abase + 512], a3 = A4[abase + 768];
#pragma unroll
      for (int bl = 0; bl < 8; ++bl)
        dot4(acc[bl], G4[bl * 256 + d4], a0, a1, a2, a3);
    }
    __syncthreads();                 // all reads of G done before overwrite

    const int t = c * L + j;
#pragma unroll
    for (int bl = 0; bl < 8; ++bl)
      H4[(t * 16 + bh + bl) * 256 + tid] = acc[bl];

    if (j < L) {
#pragma unroll
      for (int bl = 0; bl < 8; ++bl) {
        float4 xv = X4[(t * 16 + bh + bl) * 256 + tid];  // x row for next step
        float4 g;
        g.x = acc[bl].x + xv.x; g.y = acc[bl].y + xv.y;
        g.z = acc[bl].z + xv.z; g.w = acc[bl].w + xv.w;
        G4[bl * 256 + tid] = g;
      }
    }
    __syncthreads();
  }
}

// Phase 2, one chain step: s_{c+1} = A^16 * s_c + hl[(c+1)*L]
// s_c lives at the start of output-slice c. 127 sequential launches.
__global__ void p2step_kernel(const float* __restrict__ M16T, const float* __restrict__ hbuf,
                              float* out, int c) {
  const int tid = threadIdx.x;
  const int e  = blockIdx.x * 64 + (tid & 63);
  const int b0 = tid >> 6;                               // 0..3
  const float* sl = out + (size_t)c * (L * B * D);
  float*       so = out + (size_t)(c + 1) * (L * B * D);
  const float* hrow = hbuf + (size_t)(c + 1) * L * B * D; // hl at chunk boundary
  const float4* S4 = (const float4*)sl;
  float acc[4];
#pragma unroll
  for (int i = 0; i < 4; ++i) acc[i] = hrow[(b0 + 4 * i) * D + e];
#pragma unroll 2
  for (int d4 = 0; d4 < 256; ++d4) {
    float m0 = M16T[(4 * d4 + 0) * D + e];
    float m1 = M16T[(4 * d4 + 1) * D + e];
    float m2 = M16T[(4 * d4 + 2) * D + e];
    float m3 = M16T[(4 * d4 + 3) * D + e];
#pragma unroll
    for (int i = 0; i < 4; ++i) {
      float4 s4 = S4[(b0 + 4 * i) * 256 + d4];
      acc[i] += s4.x * m0 + s4.y * m1 + s4.z * m2 + s4.w * m3;
    }
  }
#pragma unroll
  for (int i = 0; i < 4; ++i) so[(b0 + 4 * i) * D + e] = acc[i];
}

// Phase 3: w_j = A^j s_c (iterated), h_t = hl_t + w_j, out_{t-1} = h^2 * sigmoid(h)
__global__ __launch_bounds__(256)
void phase3_kernel(const float* __restrict__ WnT, float* hbuf, float* out) {
  __shared__ float Wl[8 * 1024];
  const int tid = threadIdx.x;
  const int c  = blockIdx.x >> 1;
  const int bh = (blockIdx.x & 1) * 8;
  const float4* A4 = (const float4*)WnT;
  float4* H4 = (float4*)hbuf;
  float4* O4 = (float4*)out;
  float4* W4 = (float4*)Wl;
  const float4* S4 = (const float4*)(out + (size_t)c * (L * B * D));

  // read s_c (this block's b-rows == the very region this block overwrites at j=1)
#pragma unroll
  for (int bl = 0; bl < 8; ++bl)
    W4[bl * 256 + tid] = S4[(bh + bl) * 256 + tid];
  __syncthreads();

  for (int j = 1; j <= L; ++j) {
    float4 acc[8];
#pragma unroll
    for (int bl = 0; bl < 8; ++bl) { acc[bl].x = 0.f; acc[bl].y = 0.f; acc[bl].z = 0.f; acc[bl].w = 0.f; }

#pragma unroll 4
    for (int d4 = 0; d4 < 256; ++d4) {
      const int abase = d4 * 1024 + tid;
      float4 a0 = A4[abase], a1 = A4[abase + 256], a2 = A4[abase + 512], a3 = A4[abase + 768];
#pragma unroll
      for (int bl = 0; bl < 8; ++bl)
        dot4(acc[bl], W4[bl * 256 + d4], a0, a1, a2, a3);
    }
    __syncthreads();

    const int t = c * L + j;
#pragma unroll
    for (int bl = 0; bl < 8; ++bl) {
      const int hidx = (t * 16 + bh + bl) * 256 + tid;
      float4 hl = H4[hidx];
      float4 h;
      h.x = hl.x + acc[bl].x; h.y = hl.y + acc[bl].y;
      h.z = hl.z + acc[bl].z; h.w = hl.w + acc[bl].w;
      H4[hidx] = h;
      float4 o;
      o.x = h.x * h.x / (1.f + __expf(-h.x));
      o.y = h.y * h.y / (1.f + __expf(-h.y));
      o.z = h.z * h.z / (1.f + __expf(-h.z));
      o.w = h.w * h.w / (1.f + __expf(-h.w));
      O4[((t - 1) * 16 + bh + bl) * 256 + tid] = o;
      if (j < L) W4[bl * 256 + tid] = acc[bl];
    }
    __syncthreads();
  }
}

// ---------------- launch ----------------

extern "C" void kernel_launch(void* const* d_in, const int* in_sizes, int n_in,
                              void* d_out, int out_size, void* d_ws, size_t ws_size,
                              hipStream_t stream) {
  const float* x    = (const float*)d_in[0];
  const float* h0   = (const float*)d_in[1];
  const float* W    = (const float*)d_in[2];
  const float* bias = (const float*)d_in[3];
  const float* u    = (const float*)d_in[4];
  float* out  = (float*)d_out;
  float* hbuf = out + (size_t)T * B * D;   // h region follows output region
  float* ws   = (float*)d_ws;
  float* va  = ws + WS_VA;
  float* vb  = ws + WS_VB;
  float* sc  = ws + WS_SCALE;
  float* WnT = ws + WS_WNT;
  float* Pa  = ws + WS_PA;
  float* Pb  = ws + WS_PB;

  // spectral norm: 6 matvecs (normalizations cancel in sigma = ||t6||/||t5||)
  mvT_kernel<<<4, 256, 0, stream>>>(W, u, va);
  mvN_kernel<<<1024, 256, 0, stream>>>(W, va, vb);
  mvT_kernel<<<4, 256, 0, stream>>>(W, vb, va);
  mvN_kernel<<<1024, 256, 0, stream>>>(W, va, vb);
  mvT_kernel<<<4, 256, 0, stream>>>(W, vb, va);          // va = v3 direction (t5)
  mvN_kernel<<<1024, 256, 0, stream>>>(W, va, vb);       // vb = W v3 (t6)
  scale_kernel<<<1, 256, 0, stream>>>(va, vb, sc);

  transpose_scale_kernel<<<dim3(32, 32), dim3(32, 8), 0, stream>>>(W, sc, WnT);

  // (A^16)^T via 4 squarings of WnT
  sq_kernel<<<dim3(16, 16), 256, 0, stream>>>(WnT, Pa);  // (A^2)^T
  sq_kernel<<<dim3(16, 16), 256, 0, stream>>>(Pa, Pb);   // (A^4)^T
  sq_kernel<<<dim3(16, 16), 256, 0, stream>>>(Pb, Pa);   // (A^8)^T
  sq_kernel<<<dim3(16, 16), 256, 0, stream>>>(Pa, Pb);   // (A^16)^T

  init_h0_kernel<<<16, 256, 0, stream>>>(h0, hbuf, out);

  phase1_kernel<<<256, 256, 0, stream>>>(x, WnT, bias, hbuf);

  for (int c = 0; c < C - 1; ++c)
    p2step_kernel<<<16, 256, 0, stream>>>(Pb, hbuf, out, c);

  phase3_kernel<<<256, 256, 0, stream>>>(WnT, hbuf, out);
}

// Round 2
// 8015.751 us; speedup vs baseline: 1.8878x; 1.8878x over previous
//
#include <hip/hip_runtime.h>
#include <math.h>

typedef unsigned short u16;
typedef __attribute__((ext_vector_type(8))) short short8;
typedef __attribute__((ext_vector_type(4))) float f32x4;

namespace {
constexpr int D = 1024;
constexpr int B = 16;
constexpr int T = 2048;
constexpr int L = 16;
constexpr int C = T / L;          // 128 chunks
constexpr float SR  = 0.999f;
constexpr float EPS = 1e-8f;
constexpr int SLICE = L * B * D;  // 262144 floats: one out slice == one chunk's h rows
}

__device__ __forceinline__ u16 f2b(float f) {
  unsigned u = __float_as_uint(f);
  unsigned r = (u + 0x7fffu + ((u >> 16) & 1u)) >> 16;
  return (u16)r;
}
__device__ __forceinline__ float b2f(u16 v) {
  return __uint_as_float(((unsigned)v) << 16);
}

// ---------------- spectral norm (f32, small) ----------------

__global__ void mvT_kernel(const float* __restrict__ W, const float* __restrict__ vin,
                           float* __restrict__ vout) {
  int j = blockIdx.x * 256 + threadIdx.x;
  float acc = 0.f;
#pragma unroll 4
  for (int i = 0; i < D; ++i) acc += vin[i] * W[i * D + j];
  vout[j] = acc;
}

__global__ void mvN_kernel(const float* __restrict__ W, const float* __restrict__ vin,
                           float* __restrict__ vout) {
  __shared__ float red[256];
  int i = blockIdx.x, tid = threadIdx.x;
  float acc = 0.f;
  for (int j = tid; j < D; j += 256) acc += W[i * D + j] * vin[j];
  red[tid] = acc; __syncthreads();
  for (int s = 128; s > 0; s >>= 1) {
    if (tid < s) red[tid] += red[tid + s];
    __syncthreads();
  }
  if (tid == 0) vout[i] = red[0];
}

__global__ void scale_kernel(const float* __restrict__ t5, const float* __restrict__ t6,
                             float* __restrict__ scale_out) {
  __shared__ float r5[256], r6[256];
  int tid = threadIdx.x;
  float a5 = 0.f, a6 = 0.f;
  for (int i = tid; i < D; i += 256) { float x5 = t5[i], x6 = t6[i]; a5 += x5 * x5; a6 += x6 * x6; }
  r5[tid] = a5; r6[tid] = a6; __syncthreads();
  for (int s = 128; s > 0; s >>= 1) {
    if (tid < s) { r5[tid] += r5[tid + s]; r6[tid] += r6[tid + s]; }
    __syncthreads();
  }
  if (tid == 0) {
    float n5 = sqrtf(r5[0]), n6 = sqrtf(r6[0]);
    float sigma = n6 / (n5 + EPS);
    scale_out[0] = SR / (sigma + EPS);
  }
}

// Wn_bf16[e][d] = bf16(s*W[e][d]);  WnT_bf16[d][e] = bf16(s*W[e][d])
__global__ void cast_kernel(const float* __restrict__ W, const float* __restrict__ sc,
                            u16* __restrict__ WnB, u16* __restrict__ WnBT) {
  __shared__ float tile[32][33];
  float s = sc[0];
  int tx = threadIdx.x, ty = threadIdx.y;
  int bx = blockIdx.x, by = blockIdx.y;
#pragma unroll
  for (int k = 0; k < 4; ++k) {
    float v = W[(by * 32 + ty + 8 * k) * D + bx * 32 + tx];
    tile[ty + 8 * k][tx] = v;
    WnB[(by * 32 + ty + 8 * k) * D + bx * 32 + tx] = f2b(s * v);
  }
  __syncthreads();
#pragma unroll
  for (int k = 0; k < 4; ++k)
    WnBT[(bx * 32 + ty + 8 * k) * D + by * 32 + tx] = f2b(s * tile[tx][ty + 8 * k]);
}

// (O, OT) = (S*S, (S*S)^T), all bf16, via MFMA. Needs S row-major and ST row-major.
__global__ __launch_bounds__(256)
void sqb_kernel(const u16* __restrict__ S, const u16* __restrict__ ST,
                u16* __restrict__ O, u16* __restrict__ OT) {
  const int tid = threadIdx.x;
  const int lane = tid & 63, wave = tid >> 6;
  const int lrow = lane & 15, quad = lane >> 4;
  const int m0 = blockIdx.y * 64;
  const int n0 = blockIdx.x * 64 + wave * 16;
  const short8* S8  = (const short8*)S;
  const short8* ST8 = (const short8*)ST;
  f32x4 acc[4];
#pragma unroll
  for (int i = 0; i < 4; ++i) acc[i] = (f32x4){0.f, 0.f, 0.f, 0.f};
  for (int kk = 0; kk < 32; ++kk) {
    short8 bfrag = ST8[(size_t)(n0 + lrow) * 128 + kk * 4 + quad];
#pragma unroll
    for (int mt = 0; mt < 4; ++mt) {
      short8 afrag = S8[(size_t)(m0 + mt * 16 + lrow) * 128 + kk * 4 + quad];
      acc[mt] = __builtin_amdgcn_mfma_f32_16x16x32_bf16(afrag, bfrag, acc[mt], 0, 0, 0);
    }
  }
#pragma unroll
  for (int mt = 0; mt < 4; ++mt)
#pragma unroll
    for (int r = 0; r < 4; ++r) {
      int m = m0 + mt * 16 + quad * 4 + r;
      int n = n0 + lrow;
      u16 v = f2b(acc[mt][r]);
      O[(size_t)m * D + n] = v;
      OT[(size_t)n * D + m] = v;
    }
}

// h row 0 = h0; stash s_0 = h0 at out slice 0; zero barrier counters
__global__ void init_kernel(const float* __restrict__ h0, float* __restrict__ hbuf,
                            float* __restrict__ out, int* cnt, int* gen) {
  int i = blockIdx.x * 256 + threadIdx.x;
  float4 v = ((const float4*)h0)[i];
  ((float4*)hbuf)[i] = v;
  ((float4*)out)[i]  = v;
  if (i == 0) { *cnt = 0; *gen = 0; }
}

// ---------------- phase 1: per-chunk local recurrence (bf16 MFMA) ----------------
// One block per chunk. G (16 x 1024, bf16) in LDS = MFMA A operand (m=lane&15,
// k=quad*8+j contiguous => row-major). B operand from global Wn row-major
// (B[k][n] = Wn[n][k], lane reads 8 contiguous k from row n).
__global__ __launch_bounds__(256)
void phase1_kernel(const float* __restrict__ x, const u16* __restrict__ WnB,
                   const float* __restrict__ bias, float* __restrict__ hbuf) {
  __shared__ u16 G[16 * 1024];
  const int tid = threadIdx.x;
  const int c = blockIdx.x;
  const int lane = tid & 63, wave = tid >> 6;
  const int lrow = lane & 15, quad = lane >> 4;
  const int nbase = wave * 256;
  const short8* Wn8 = (const short8*)WnB;
  const short8* G8 = (const short8*)G;

  {
    const float4* X4 = (const float4*)(x + (size_t)c * SLICE);
    ushort4* G4 = (ushort4*)G;
    for (int i = tid; i < 4096; i += 256) {
      float4 v = X4[i];
      ushort4 g; g.x = f2b(v.x); g.y = f2b(v.y); g.z = f2b(v.z); g.w = f2b(v.w);
      G4[i] = g;
    }
  }

  float bcol[16];
#pragma unroll
  for (int tl = 0; tl < 16; ++tl) bcol[tl] = bias[nbase + tl * 16 + lrow];

  __syncthreads();

  for (int j = 1; j <= L; ++j) {
    f32x4 acc[16];
#pragma unroll
    for (int tl = 0; tl < 16; ++tl)
      acc[tl] = (f32x4){bcol[tl], bcol[tl], bcol[tl], bcol[tl]};

#pragma unroll
    for (int tp = 0; tp < 8; ++tp) {
      const short8* B0 = Wn8 + (size_t)(nbase + tp * 32 + lrow) * 128;
      const short8* B1 = B0 + 16 * 128;
      f32x4 a0 = acc[2 * tp], a1 = acc[2 * tp + 1];
#pragma unroll 8
      for (int kk = 0; kk < 32; ++kk) {
        short8 av = G8[lrow * 128 + kk * 4 + quad];
        a0 = __builtin_amdgcn_mfma_f32_16x16x32_bf16(av, B0[kk * 4 + quad], a0, 0, 0, 0);
        a1 = __builtin_amdgcn_mfma_f32_16x16x32_bf16(av, B1[kk * 4 + quad], a1, 0, 0, 0);
      }
      acc[2 * tp] = a0; acc[2 * tp + 1] = a1;
    }

    __syncthreads();   // all waves done reading G before overwrite

    const int t = c * L + j;
    float* hrow = hbuf + (size_t)t * (B * D);
    const float* xrow = x + (size_t)t * (B * D);  // only dereferenced when j < L
#pragma unroll
    for (int tl = 0; tl < 16; ++tl) {
      const int n = nbase + tl * 16 + lrow;
#pragma unroll
      for (int r = 0; r < 4; ++r) {
        const int b = quad * 4 + r;
        float hv = acc[tl][r];
        hrow[b * 1024 + n] = hv;
        if (j < L) G[b * 1024 + n] = f2b(hv + xrow[b * 1024 + n]);
      }
    }
    __syncthreads();
  }
}

// ---------------- phase 2: boundary chain, one kernel, grid barrier ----------------

__device__ __forceinline__ void grid_bar(int* cnt, int* gen, int nblk) {
  __syncthreads();
  if (threadIdx.x == 0) {
    __threadfence();
    int g = __hip_atomic_load(gen, __ATOMIC_RELAXED, __HIP_MEMORY_SCOPE_AGENT);
    int prev = __hip_atomic_fetch_add(cnt, 1, __ATOMIC_ACQ_REL, __HIP_MEMORY_SCOPE_AGENT);
    if (prev == nblk - 1) {
      __hip_atomic_store(cnt, 0, __ATOMIC_RELAXED, __HIP_MEMORY_SCOPE_AGENT);
      __hip_atomic_fetch_add(gen, 1, __ATOMIC_RELEASE, __HIP_MEMORY_SCOPE_AGENT);
    } else {
      while (__hip_atomic_load(gen, __ATOMIC_ACQUIRE, __HIP_MEMORY_SCOPE_AGENT) == g)
        __builtin_amdgcn_s_sleep(1);
    }
  }
  __syncthreads();
}

// s_{c+1} = A16 * s_c + hl[(c+1)*L];  s_c stashed at out slice c start.
// 64 blocks x 256 threads; thread computes one (b, e) output per step.
__global__ __launch_bounds__(256)
void phase2_kernel(const u16* __restrict__ A16T, const float* __restrict__ hbuf,
                   float* __restrict__ out, int* cnt, int* gen) {
  const int tid = threadIdx.x;
  const int el = tid & 15, b = tid >> 4;
  const int e = blockIdx.x * 16 + el;
  const int nblk = gridDim.x;
  for (int c = 0; c < C - 1; ++c) {
    const float* s = out + (size_t)c * SLICE + b * 1024;
    const float* hl = hbuf + (size_t)(c + 1) * SLICE;
    float acc = hl[b * 1024 + e];
#pragma unroll 8
    for (int d = 0; d < 1024; ++d)
      acc += s[d] * b2f(A16T[(size_t)d * 1024 + e]);
    out[(size_t)(c + 1) * SLICE + b * 1024 + e] = acc;
    grid_bar(cnt, gen, nblk);
  }
}

// ---------------- phase 3: w_j = A^j s_c; h = hl + w; out = h^2*sigmoid(h) ----------------

__global__ __launch_bounds__(256)
void phase3_kernel(const u16* __restrict__ WnB, float* __restrict__ hbuf,
                   float* __restrict__ out) {
  __shared__ u16 G[16 * 1024];
  const int tid = threadIdx.x;
  const int c = blockIdx.x;
  const int lane = tid & 63, wave = tid >> 6;
  const int lrow = lane & 15, quad = lane >> 4;
  const int nbase = wave * 256;
  const short8* Wn8 = (const short8*)WnB;
  const short8* G8 = (const short8*)G;

  {
    const float4* S4 = (const float4*)(out + (size_t)c * SLICE);
    ushort4* G4 = (ushort4*)G;
    for (int i = tid; i < 4096; i += 256) {
      float4 v = S4[i];
      ushort4 g; g.x = f2b(v.x); g.y = f2b(v.y); g.z = f2b(v.z); g.w = f2b(v.w);
      G4[i] = g;
    }
  }
  __syncthreads();

  for (int j = 1; j <= L; ++j) {
    f32x4 acc[16];
#pragma unroll
    for (int tl = 0; tl < 16; ++tl) acc[tl] = (f32x4){0.f, 0.f, 0.f, 0.f};

#pragma unroll
    for (int tp = 0; tp < 8; ++tp) {
      const short8* B0 = Wn8 + (size_t)(nbase + tp * 32 + lrow) * 128;
      const short8* B1 = B0 + 16 * 128;
      f32x4 a0 = acc[2 * tp], a1 = acc[2 * tp + 1];
#pragma unroll 8
      for (int kk = 0; kk < 32; ++kk) {
        short8 av = G8[lrow * 128 + kk * 4 + quad];
        a0 = __builtin_amdgcn_mfma_f32_16x16x32_bf16(av, B0[kk * 4 + quad], a0, 0, 0, 0);
        a1 = __builtin_amdgcn_mfma_f32_16x16x32_bf16(av, B1[kk * 4 + quad], a1, 0, 0, 0);
      }
      acc[2 * tp] = a0; acc[2 * tp + 1] = a1;
    }

    __syncthreads();

    const int t = c * L + j;
    float* hrow = hbuf + (size_t)t * (B * D);
    float* orow = out + (size_t)(t - 1) * (B * D);
#pragma unroll
    for (int tl = 0; tl < 16; ++tl) {
      const int n = nbase + tl * 16 + lrow;
#pragma unroll
      for (int r = 0; r < 4; ++r) {
        const int b = quad * 4 + r;
        float wv = acc[tl][r];
        float hv = hrow[b * 1024 + n] + wv;
        hrow[b * 1024 + n] = hv;
        float o = hv * hv / (1.f + __expf(-hv));
        orow[b * 1024 + n] = o;
        if (j < L) G[b * 1024 + n] = f2b(wv);
      }
    }
    __syncthreads();
  }
}

// ---------------- launch ----------------

extern "C" void kernel_launch(void* const* d_in, const int* in_sizes, int n_in,
                              void* d_out, int out_size, void* d_ws, size_t ws_size,
                              hipStream_t stream) {
  const float* x    = (const float*)d_in[0];
  const float* h0   = (const float*)d_in[1];
  const float* W    = (const float*)d_in[2];
  const float* bias = (const float*)d_in[3];
  const float* u    = (const float*)d_in[4];
  float* out  = (float*)d_out;
  float* hbuf = out + (size_t)T * B * D;

  char* wsb = (char*)d_ws;
  float* va = (float*)wsb;
  float* vb = (float*)(wsb + 4096);
  float* sc = (float*)(wsb + 8192);
  int* cnt  = (int*)(wsb + 8192 + 64);
  int* gen  = cnt + 1;
  u16* WnB  = (u16*)(wsb + 16384);
  u16* WnBT = WnB  + (size_t)D * D;
  u16* P1   = WnBT + (size_t)D * D;
  u16* P1T  = P1   + (size_t)D * D;
  u16* P2   = P1T  + (size_t)D * D;
  u16* P2T  = P2   + (size_t)D * D;

  // spectral norm: 6 matvecs; sigma = ||W v3|| / ||v3||
  mvT_kernel<<<4, 256, 0, stream>>>(W, u, va);
  mvN_kernel<<<1024, 256, 0, stream>>>(W, va, vb);
  mvT_kernel<<<4, 256, 0, stream>>>(W, vb, va);
  mvN_kernel<<<1024, 256, 0, stream>>>(W, va, vb);
  mvT_kernel<<<4, 256, 0, stream>>>(W, vb, va);
  mvN_kernel<<<1024, 256, 0, stream>>>(W, va, vb);
  scale_kernel<<<1, 256, 0, stream>>>(va, vb, sc);

  cast_kernel<<<dim3(32, 32), dim3(32, 8), 0, stream>>>(W, sc, WnB, WnBT);

  // (A^16)^T via 4 bf16 MFMA squarings (keep both orientations each level)
  sqb_kernel<<<dim3(16, 16), 256, 0, stream>>>(WnB, WnBT, P1, P1T);  // A^2
  sqb_kernel<<<dim3(16, 16), 256, 0, stream>>>(P1, P1T, P2, P2T);    // A^4
  sqb_kernel<<<dim3(16, 16), 256, 0, stream>>>(P2, P2T, P1, P1T);    // A^8
  sqb_kernel<<<dim3(16, 16), 256, 0, stream>>>(P1, P1T, P2, P2T);    // A^16

  init_kernel<<<16, 256, 0, stream>>>(h0, hbuf, out, cnt, gen);

  phase1_kernel<<<C, 256, 0, stream>>>(x, WnB, bias, hbuf);

  phase2_kernel<<<64, 256, 0, stream>>>(P2T, hbuf, out, cnt, gen);

  phase3_kernel<<<C, 256, 0, stream>>>(WnB, hbuf, out);
}